// Round 6
// baseline (179.858 us; speedup 1.0000x reference)
//
#include <hip/hip_runtime.h>
#include <hip/hip_bf16.h>
#include <stdint.h>

#define N_PTS 8192
#define M_EDGES 131072
#define CIN 512
#define QKV_COLS 1536

typedef __bf16 bf16x8 __attribute__((ext_vector_type(8)));
typedef float f32x4 __attribute__((ext_vector_type(4)));

#define GAS __attribute__((address_space(1)))
#define LAS __attribute__((address_space(3)))

__device__ __forceinline__ void gload_lds16(const void* g, void* l) {
  __builtin_amdgcn_global_load_lds((const GAS void*)g, (LAS void*)l, 16, 0, 0);
}

// ---- prep: cast_a | cast_bt | cast qk-tables | build vtT | edge_setup, one launch ----
__global__ __launch_bounds__(256) void prep_kernel(
    const float* __restrict__ xF, const float* __restrict__ W,
    const float* __restrict__ qt, const float* __restrict__ kt,
    const float* __restrict__ vt, const int* __restrict__ pairs,
    const float* __restrict__ xc,
    __bf16* __restrict__ A, __bf16* __restrict__ BT,
    __bf16* __restrict__ qtb, __bf16* __restrict__ ktb, __bf16* __restrict__ vtT,
    int* __restrict__ qi_a, unsigned* __restrict__ pack0, int* __restrict__ cnt) {
  __shared__ float tile[32][33];
  int b = blockIdx.x;
  int tid = threadIdx.x;
  if (b < 4096) {  // cast x_F -> bf16 A
    int base = (b * 256 + tid) * 4;
    float4 v = *(const float4*)(xF + base);
    A[base + 0] = (__bf16)v.x;
    A[base + 1] = (__bf16)v.y;
    A[base + 2] = (__bf16)v.z;
    A[base + 3] = (__bf16)v.w;
  } else if (b < 4864) {  // transpose+cast W (512x1536) -> BT (1536x512)
    int blk = b - 4096;
    int bk = blk & 15, bn = blk >> 4;
    int x = tid & 31, y = tid >> 5;
#pragma unroll
    for (int j = 0; j < 4; j++) {
      int r = y + j * 8;
      tile[r][x] = W[(size_t)(bk * 32 + r) * QKV_COLS + bn * 32 + x];
    }
    __syncthreads();
#pragma unroll
    for (int j = 0; j < 4; j++) {
      int r = y + j * 8;
      BT[(size_t)(bn * 32 + r) * CIN + bk * 32 + x] = (__bf16)tile[x][r];
    }
  } else if (b < 5152) {  // cast qt/kt tables -> [h][ab][d] bf16
    int i = (b - 4864) * 256 + tid;
    int d = i & 63, h = (i >> 6) & 7, ab = i >> 9;
    int po = (h * 144 + ab) * 64 + d;
    qtb[po] = (__bf16)qt[i];
    ktb[po] = (__bf16)kt[i];
  } else if (b < 5472) {  // vtT[h][d][p] bf16, p in [0,160), zero-padded past 144
    int i = (b - 5152) * 256 + tid;  // 8*64*160 = 81920
    int p = i % 160;
    int d = (i / 160) & 63;
    int h = i / 10240;
    vtT[i] = (p < 144) ? (__bf16)vt[p * 512 + h * 64 + d] : (__bf16)0.f;
  } else {  // edge setup
    int m = (b - 5472) * 256 + tid;
    int qi = pairs[m], ki = pairs[M_EDGES + m];
    unsigned pb = 0;
#pragma unroll
    for (int a = 0; a < 3; a++) {
      float rel = (xc[qi * 3 + a] - xc[ki * 3 + a]) / 0.05f + 24.0f;
      int bb = (int)rel;
      bb = bb < 0 ? 0 : (bb > 47 ? 47 : bb);
      pb |= (unsigned)bb << (6 * a);
    }
    qi_a[m] = qi;
    pack0[m] = (unsigned)ki | (pb << 13);
    atomicAdd(&cnt[qi], 1);
  }
}

// ---- bf16 MFMA GEMM, 64x128 tile, BK=64, XOR-swizzled LDS, double-buffered.
// grid = (bn=12, bm=128): consecutive blocks share one A tile (A streamed once). ----
__global__ __launch_bounds__(256) void gemm_qkv(const __bf16* __restrict__ A,
                                                const __bf16* __restrict__ BT,
                                                const float* __restrict__ bias,
                                                __bf16* __restrict__ qb,
                                                __bf16* __restrict__ kb,
                                                __bf16* __restrict__ vb) {
  __shared__ __align__(16) char At[2][64 * 128];   // 2x8KB
  __shared__ __align__(16) char Bt[2][128 * 128];  // 2x16KB
  int tid = threadIdx.x;
  int w = tid >> 6, l = tid & 63;
  int bn = blockIdx.x, bm = blockIdx.y;
  int wm = w & 1, wn = w >> 1;
  f32x4 acc[2][4] = {};
  const char* Ab = (const char*)A;
  const char* Bb = (const char*)BT;
  int lr = l & 15;
  int lk = (l >> 4) * 16;
  int xr = (lr & 7) << 4;

  auto stage = [&](int tk, int buf) {
#pragma unroll
    for (int r = 0; r < 2; r++) {
      int flat = r * 4096 + tid * 16;
      int row = flat >> 7, colb = flat & 127;
      int gcolb = colb ^ ((row & 7) << 4);
      gload_lds16(Ab + ((size_t)(bm * 64 + row) * CIN + tk * 64) * 2 + gcolb,
                  At[buf] + r * 4096 + w * 1024);
    }
#pragma unroll
    for (int r = 0; r < 4; r++) {
      int flat = r * 4096 + tid * 16;
      int row = flat >> 7, colb = flat & 127;
      int gcolb = colb ^ ((row & 7) << 4);
      gload_lds16(Bb + ((size_t)(bn * 128 + row) * CIN + tk * 64) * 2 + gcolb,
                  Bt[buf] + r * 4096 + w * 1024);
    }
  };

  stage(0, 0);
  __syncthreads();
  int cur = 0;
  for (int kt = 0; kt < 8; kt++) {
    if (kt < 7) stage(kt + 1, cur ^ 1);  // prefetch next tile; drained by barrier below
#pragma unroll
    for (int ks = 0; ks < 2; ks++) {
      bf16x8 af[2], bfr[4];
      int cs = (ks * 64 + lk) ^ xr;
#pragma unroll
      for (int mf = 0; mf < 2; mf++) af[mf] = *(const bf16x8*)(At[cur] + (wm * 32 + mf * 16 + lr) * 128 + cs);
#pragma unroll
      for (int nf = 0; nf < 4; nf++) bfr[nf] = *(const bf16x8*)(Bt[cur] + (wn * 64 + nf * 16 + lr) * 128 + cs);
#pragma unroll
      for (int mf = 0; mf < 2; mf++)
#pragma unroll
        for (int nf = 0; nf < 4; nf++)
          acc[mf][nf] = __builtin_amdgcn_mfma_f32_16x16x32_bf16(af[mf], bfr[nf], acc[mf][nf], 0, 0, 0);
    }
    __syncthreads();
    cur ^= 1;
  }

  int lg = l >> 4;
#pragma unroll
  for (int mf = 0; mf < 2; mf++) {
#pragma unroll
    for (int nf = 0; nf < 4; nf++) {
      int gc = bn * 128 + wn * 64 + nf * 16 + lr;
      float b = bias[gc];
      int which = gc >> 9;
      int col = gc & 511;
      __bf16* dst = which == 0 ? qb : (which == 1 ? kb : vb);
      float scale = which == 0 ? 0.125f : 1.0f;
#pragma unroll
      for (int j = 0; j < 4; j++) {
        int gr = bm * 64 + wm * 32 + mf * 16 + lg * 4 + j;
        dst[(size_t)gr * 512 + col] = (__bf16)((acc[mf][nf][j] + b) * scale);
      }
    }
  }
}

// ---- table_dot (q and k via z): out[n][ab*8+h] = src[n,h,:] . tab[h,ab,:] ----
__global__ __launch_bounds__(256) void table_dot(const __bf16* __restrict__ qb,
                                                 const __bf16* __restrict__ kb,
                                                 const __bf16* __restrict__ qtb,
                                                 const __bf16* __restrict__ ktb,
                                                 __bf16* __restrict__ qdot,
                                                 __bf16* __restrict__ kdot) {
  __shared__ __align__(16) char As[128 * 128];
  __shared__ __align__(16) char Bs[144 * 128];
  int nt = blockIdx.x, h = blockIdx.y, z = blockIdx.z;
  const __bf16* src = z ? kb : qb;
  const __bf16* tab = z ? ktb : qtb;
  __bf16* out = z ? kdot : qdot;
  int tid = threadIdx.x, w = tid >> 6, l = tid & 63;
  const char* sb = (const char*)src;
  const char* tb = (const char*)tab + (size_t)h * 144 * 128;
#pragma unroll
  for (int p = 0; p < 4; p++) {
    int flat = p * 4096 + tid * 16;
    int row = flat >> 7, colb = flat & 127;
    int gcolb = colb ^ ((row & 7) << 4);
    gload_lds16(sb + (size_t)(nt * 128 + row) * 1024 + h * 128 + gcolb, As + p * 4096 + w * 1024);
    gload_lds16(tb + row * 128 + gcolb, Bs + p * 4096 + w * 1024);
  }
  if (w < 2) {
    int flat = 16384 + w * 1024 + l * 16;
    int row = flat >> 7, colb = flat & 127;
    int gcolb = colb ^ ((row & 7) << 4);
    gload_lds16(tb + row * 128 + gcolb, Bs + 16384 + w * 1024);
  }
  __syncthreads();

  f32x4 acc[2][9] = {};
  int lr = l & 15, lk = (l >> 4) * 16;
  int xr = (lr & 7) << 4;
#pragma unroll
  for (int ks = 0; ks < 2; ks++) {
    bf16x8 af[2], bf[9];
    int cs = (ks * 64 + lk) ^ xr;
#pragma unroll
    for (int mf = 0; mf < 2; mf++)
      af[mf] = *(const bf16x8*)(As + (w * 32 + mf * 16 + lr) * 128 + cs);
#pragma unroll
    for (int nf = 0; nf < 9; nf++)
      bf[nf] = *(const bf16x8*)(Bs + (nf * 16 + lr) * 128 + cs);
#pragma unroll
    for (int mf = 0; mf < 2; mf++)
#pragma unroll
      for (int nf = 0; nf < 9; nf++)
        acc[mf][nf] = __builtin_amdgcn_mfma_f32_16x16x32_bf16(af[mf], bf[nf], acc[mf][nf], 0, 0, 0);
  }

  int lg = l >> 4;
#pragma unroll
  for (int mf = 0; mf < 2; mf++)
#pragma unroll
    for (int nf = 0; nf < 9; nf++)
#pragma unroll
      for (int j = 0; j < 4; j++) {
        int n = nt * 128 + w * 32 + mf * 16 + lg * 4 + j;
        int ab = nf * 16 + lr;
        out[(size_t)n * 1152 + ab * 8 + h] = (__bf16)acc[mf][nf][j];
      }
}

// ---- scan: 256 threads, 32 counts each ----
__global__ __launch_bounds__(256) void scan_kernel(const int* __restrict__ cnt,
                                                   int* __restrict__ off,
                                                   int* __restrict__ cursor) {
  __shared__ int wsum[4];
  int tid = threadIdx.x, lane = tid & 63, w = tid >> 6;
  int local[32];
  int s = 0;
#pragma unroll
  for (int i = 0; i < 8; i++) {
    int4 v = ((const int4*)cnt)[tid * 8 + i];
    local[i * 4 + 0] = v.x; local[i * 4 + 1] = v.y;
    local[i * 4 + 2] = v.z; local[i * 4 + 3] = v.w;
    s += v.x + v.y + v.z + v.w;
  }
  int incl = s;
#pragma unroll
  for (int d = 1; d < 64; d <<= 1) {
    int t = __shfl_up(incl, d, 64);
    if (lane >= d) incl += t;
  }
  if (lane == 63) wsum[w] = incl;
  __syncthreads();
  int woff = 0;
#pragma unroll
  for (int j = 0; j < 4; j++) woff += (j < w) ? wsum[j] : 0;
  int run = woff + incl - s;
  int base = tid * 32;
#pragma unroll
  for (int i = 0; i < 32; i++) {
    off[base + i] = run;
    cursor[base + i] = run;
    run += local[i];
  }
  if (tid == 255) off[N_PTS] = run;
}

// ---- scatter edges into CSR order ----
__global__ void scatter_k(const int* __restrict__ qi_a, const unsigned* __restrict__ pack0,
                          int* __restrict__ cursor, int* __restrict__ qi_s,
                          unsigned* __restrict__ epack) {
  int m = blockIdx.x * blockDim.x + threadIdx.x;
  if (m < M_EDGES) {
    int qi = qi_a[m];
    int pos = atomicAdd(&cursor[qi], 1);
    qi_s[pos] = qi;
    epack[pos] = pack0[m];
  }
}

// ---- edge_bias: eb[e][h] = sum_a qdot[qi,a,bin]+kdot[ki,a,bin] ----
__global__ void edge_bias(const int* __restrict__ qi_s, const unsigned* __restrict__ epack,
                          const __bf16* __restrict__ qdot, const __bf16* __restrict__ kdot,
                          float* __restrict__ eb) {
  int t = blockIdx.x * 256 + threadIdx.x;
  int e = t >> 3, h = t & 7;
  unsigned pk = epack[e];
  int ki = pk & 8191;
  unsigned pb = pk >> 13;
  int qi = qi_s[e];
  int a0 = ((int)(pb & 63)) * 8 + h;
  int a1 = (48 + (int)((pb >> 6) & 63)) * 8 + h;
  int a2 = (96 + (int)((pb >> 12) & 63)) * 8 + h;
  const __bf16* qd = qdot + qi * 1152;
  const __bf16* kd = kdot + ki * 1152;
  eb[t] = (float)qd[a0] + (float)qd[a1] + (float)qd[a2] +
          (float)kd[a0] + (float)kd[a1] + (float)kd[a2];
}

// ---- fused attention: block=query, wave=head, 16 edges in flight (2x unroll).
// Writes unnormalized num (into out), den, per-(query,head) 160-bin histogram Hb. ----
__global__ __launch_bounds__(512) void attn_kernel(
    const __bf16* __restrict__ qb, const __bf16* __restrict__ kb,
    const __bf16* __restrict__ vb, const float* __restrict__ eb,
    const int* __restrict__ off, const unsigned* __restrict__ epack,
    float* __restrict__ num, float* __restrict__ den, __bf16* __restrict__ Hb) {
  __shared__ float hist[8 * 160];
  int n = blockIdx.x;
  int tid = threadIdx.x;
  int h = tid >> 6, l = tid & 63;
  int es = l >> 3, dg = l & 7;
  int tcol = h * 64 + dg * 8;

  for (int i = tid; i < 1280; i += 512) hist[i] = 0.f;
  __syncthreads();

  bf16x8 q8 = *(const bf16x8*)(qb + (n << 9) + tcol);
  float qv[8];
#pragma unroll
  for (int j = 0; j < 8; j++) qv[j] = (float)q8[j];

  float acc[8] = {0.f, 0.f, 0.f, 0.f, 0.f, 0.f, 0.f, 0.f};
  float dn = 0.f;
  int e0 = off[n], e1 = off[n + 1];
  float* hh = hist + h * 160;
  int hsh = dg * 6;        // per-lane histogram axis (lanes dg=0..2 active)
  int hbase = dg * 48;

  for (int base = e0; base < e1; base += 16) {
    int eA = base + es;
    int eB = base + 8 + es;
    int cA = eA < e1 ? eA : e1 - 1;
    int cB = eB < e1 ? eB : e1 - 1;
    unsigned pkA = epack[cA], pkB = epack[cB];
    float ebA = eb[(cA << 3) + h], ebB = eb[(cB << 3) + h];
    int kiA = pkA & 8191, kiB = pkB & 8191;
    bf16x8 kA8 = *(const bf16x8*)(kb + (kiA << 9) + tcol);
    bf16x8 vA8 = *(const bf16x8*)(vb + (kiA << 9) + tcol);
    bf16x8 kB8 = *(const bf16x8*)(kb + (kiB << 9) + tcol);
    bf16x8 vB8 = *(const bf16x8*)(vb + (kiB << 9) + tcol);
    float p1 = 0.f, p2 = 0.f;
#pragma unroll
    for (int j = 0; j < 8; j++) {
      p1 += qv[j] * (float)kA8[j];
      p2 += qv[j] * (float)kB8[j];
    }
    p1 += __shfl_xor(p1, 1, 64);
    p2 += __shfl_xor(p2, 1, 64);
    p1 += __shfl_xor(p1, 2, 64);
    p2 += __shfl_xor(p2, 2, 64);
    p1 += __shfl_xor(p1, 4, 64);
    p2 += __shfl_xor(p2, 4, 64);
    p1 += ebA;
    p2 += ebB;
    float x1 = (eA < e1) ? __expf(p1) : 0.f;
    float x2 = (eB < e1) ? __expf(p2) : 0.f;
    dn += x1 + x2;
#pragma unroll
    for (int j = 0; j < 8; j++)
      acc[j] += x1 * (float)vA8[j] + x2 * (float)vB8[j];
    if (dg < 3) {  // 3 lanes handle the 3 axes in parallel
      unsigned pbA = pkA >> 13, pbB = pkB >> 13;
      atomicAdd(hh + hbase + ((pbA >> hsh) & 63), x1);
      atomicAdd(hh + hbase + ((pbB >> hsh) & 63), x2);
    }
  }

#pragma unroll
  for (int s = 8; s <= 32; s <<= 1) {
    dn += __shfl_xor(dn, s, 64);
#pragma unroll
    for (int j = 0; j < 8; j++) acc[j] += __shfl_xor(acc[j], s, 64);
  }

  if (l < 8) {
    float* op = num + (n << 9) + h * 64 + l * 8;
    f32x4 o0 = {acc[0], acc[1], acc[2], acc[3]};
    f32x4 o1 = {acc[4], acc[5], acc[6], acc[7]};
    *(f32x4*)op = o0;
    *(f32x4*)(op + 4) = o1;
  }
  if (l == 0) den[n * 8 + h] = dn;
  __syncthreads();
  for (int i = tid; i < 1280; i += 512) Hb[(size_t)n * 1280 + i] = (__bf16)hist[i];
}

// ---- finish: out = (num + Hb @ vtT) * invden.  Per block: 128 queries x 1 head. ----
__global__ __launch_bounds__(256) void finish_kernel(const __bf16* __restrict__ Hb,
                                                     const __bf16* __restrict__ vtT,
                                                     const float* __restrict__ den,
                                                     float* __restrict__ out) {
  __shared__ __align__(16) char As[2][128 * 64];  // 2x8KB
  __shared__ __align__(16) char Bs[2][64 * 64];   // 2x4KB
  int nt = blockIdx.x, h = blockIdx.y;
  int tid = threadIdx.x, w = tid >> 6, l = tid & 63;
  int lr = l & 15, lk = (l >> 4) * 16;
  int xr = (lr & 3) << 4;
  const char* Ab = (const char*)Hb;
  const char* Bb = (const char*)vtT;
  f32x4 acc[2][4] = {};

  auto stage = [&](int tk, int buf) {
#pragma unroll
    for (int c = 0; c < 2; c++) {
      int flat = c * 4096 + tid * 16;
      int row = flat >> 6, colb = flat & 63;
      int gcolb = colb ^ ((row & 3) << 4);
      gload_lds16(Ab + ((size_t)(nt * 128 + row) * 1280 + h * 160 + tk * 32) * 2 + gcolb,
                  As[buf] + c * 4096 + w * 1024);
    }
    {
      int flat = tid * 16;
      int row = flat >> 6, colb = flat & 63;
      int gcolb = colb ^ ((row & 3) << 4);
      gload_lds16(Bb + ((size_t)(h * 64 + row) * 160 + tk * 32) * 2 + gcolb,
                  Bs[buf] + w * 1024);
    }
  };

  stage(0, 0);
  __syncthreads();
  int cur = 0;
  for (int kt = 0; kt < 5; kt++) {
    if (kt < 4) stage(kt + 1, cur ^ 1);
    bf16x8 af[2], bf[4];
    int cs = lk ^ xr;
#pragma unroll
    for (int mf = 0; mf < 2; mf++) af[mf] = *(const bf16x8*)(As[cur] + (w * 32 + mf * 16 + lr) * 64 + cs);
#pragma unroll
    for (int nf = 0; nf < 4; nf++) bf[nf] = *(const bf16x8*)(Bs[cur] + (nf * 16 + lr) * 64 + cs);
#pragma unroll
    for (int mf = 0; mf < 2; mf++)
#pragma unroll
      for (int nf = 0; nf < 4; nf++)
        acc[mf][nf] = __builtin_amdgcn_mfma_f32_16x16x32_bf16(af[mf], bf[nf], acc[mf][nf], 0, 0, 0);
    __syncthreads();
    cur ^= 1;
  }

  int lg = l >> 4;
#pragma unroll
  for (int mf = 0; mf < 2; mf++) {
#pragma unroll
    for (int j = 0; j < 4; j++) {
      int n = nt * 128 + w * 32 + mf * 16 + lg * 4 + j;
      float dnv = den[n * 8 + h];
      float inv = dnv > 0.f ? 1.f / dnv : 0.f;
#pragma unroll
      for (int nf = 0; nf < 4; nf++) {
        int gi = (n << 9) + h * 64 + nf * 16 + lr;
        out[gi] = (out[gi] + acc[mf][nf][j]) * inv;
      }
    }
  }
}

extern "C" void kernel_launch(void* const* d_in, const int* in_sizes, int n_in,
                              void* d_out, int out_size, void* d_ws, size_t ws_size,
                              hipStream_t stream) {
  const float* xF = (const float*)d_in[0];
  const float* xC = (const float*)d_in[1];
  const int* pairs = (const int*)d_in[2];
  const float* W = (const float*)d_in[3];
  const float* bias = (const float*)d_in[4];
  const float* qt = (const float*)d_in[5];
  const float* kt = (const float*)d_in[6];
  const float* vt = (const float*)d_in[7];
  float* out = (float*)d_out;

  char* ws = (char*)d_ws;
  size_t o = 0;
  auto alloc = [&](size_t bytes) {
    void* p = ws + o;
    o = (o + bytes + 255) & ~(size_t)255;
    return p;
  };
  // region 0: A+BT live only until gemm_qkv; Hb (written by attn, later) aliases them.
  char* region0 = (char*)alloc((size_t)N_PTS * 1280 * 2);  // 20.97 MB
  __bf16* A = (__bf16*)region0;                      // 8 MB
  __bf16* BT = (__bf16*)(region0 + (size_t)N_PTS * CIN * 2);  // 1.5 MB
  __bf16* Hb = (__bf16*)region0;                     // aliases A/BT after gemm
  __bf16* qb = (__bf16*)alloc((size_t)N_PTS * 512 * 2);
  __bf16* kb = (__bf16*)alloc((size_t)N_PTS * 512 * 2);
  __bf16* vb = (__bf16*)alloc((size_t)N_PTS * 512 * 2);
  __bf16* qtb = (__bf16*)alloc((size_t)8 * 144 * 64 * 2);
  __bf16* ktb = (__bf16*)alloc((size_t)8 * 144 * 64 * 2);
  __bf16* vtT = (__bf16*)alloc((size_t)8 * 64 * 160 * 2);
  __bf16* qdot = (__bf16*)alloc((size_t)N_PTS * 1152 * 2);
  __bf16* kdot = (__bf16*)alloc((size_t)N_PTS * 1152 * 2);
  float* eb = (float*)alloc((size_t)M_EDGES * 8 * 4);
  float* den = (float*)alloc((size_t)N_PTS * 8 * 4);
  int* qi_a = (int*)alloc(M_EDGES * 4);
  unsigned* pack0 = (unsigned*)alloc(M_EDGES * 4);
  int* qi_s = (int*)alloc(M_EDGES * 4);
  unsigned* epack = (unsigned*)alloc(M_EDGES * 4);
  int* cnt = (int*)alloc(N_PTS * 4);
  int* off = (int*)alloc((N_PTS + 1) * 4);
  int* cursor = (int*)alloc(N_PTS * 4);

  hipMemsetAsync(cnt, 0, N_PTS * 4, stream);

  prep_kernel<<<5984, 256, 0, stream>>>(xF, W, qt, kt, vt, pairs, xC,
                                        A, BT, qtb, ktb, vtT, qi_a, pack0, cnt);
  scan_kernel<<<1, 256, 0, stream>>>(cnt, off, cursor);
  scatter_k<<<M_EDGES / 256, 256, 0, stream>>>(qi_a, pack0, cursor, qi_s, epack);
  gemm_qkv<<<dim3(QKV_COLS / 128, N_PTS / 64), 256, 0, stream>>>(A, BT, bias, qb, kb, vb);
  table_dot<<<dim3(N_PTS / 128, 8, 2), 256, 0, stream>>>(qb, kb, qtb, ktb, qdot, kdot);
  edge_bias<<<(M_EDGES * 8) / 256, 256, 0, stream>>>(qi_s, epack, qdot, kdot, eb);
  attn_kernel<<<N_PTS, 512, 0, stream>>>(qb, kb, vb, eb, off, epack, out, den, Hb);
  finish_kernel<<<dim3(N_PTS / 128, 8), 256, 0, stream>>>(Hb, vtT, den, out);
}

// Round 7
// 164.912 us; speedup vs baseline: 1.0906x; 1.0906x over previous
//
#include <hip/hip_runtime.h>
#include <hip/hip_bf16.h>
#include <stdint.h>

#define N_PTS 8192
#define M_EDGES 131072
#define CIN 512
#define QKV_COLS 1536

typedef __bf16 bf16x8 __attribute__((ext_vector_type(8)));
typedef float f32x4 __attribute__((ext_vector_type(4)));

#define GAS __attribute__((address_space(1)))
#define LAS __attribute__((address_space(3)))

__device__ __forceinline__ void gload_lds16(const void* g, void* l) {
  __builtin_amdgcn_global_load_lds((const GAS void*)g, (LAS void*)l, 16, 0, 0);
}

// ---- prep: cast_a | cast_bt | cast qk-tables | build vtT | edge_setup, one launch ----
__global__ __launch_bounds__(256) void prep_kernel(
    const float* __restrict__ xF, const float* __restrict__ W,
    const float* __restrict__ qt, const float* __restrict__ kt,
    const float* __restrict__ vt, const int* __restrict__ pairs,
    const float* __restrict__ xc,
    __bf16* __restrict__ A, __bf16* __restrict__ BT,
    __bf16* __restrict__ qtb, __bf16* __restrict__ ktb, __bf16* __restrict__ vtT,
    int* __restrict__ qi_a, unsigned* __restrict__ pack0, int* __restrict__ cnt) {
  __shared__ float tile[32][33];
  int b = blockIdx.x;
  int tid = threadIdx.x;
  if (b < 4096) {  // cast x_F -> bf16 A
    int base = (b * 256 + tid) * 4;
    float4 v = *(const float4*)(xF + base);
    A[base + 0] = (__bf16)v.x;
    A[base + 1] = (__bf16)v.y;
    A[base + 2] = (__bf16)v.z;
    A[base + 3] = (__bf16)v.w;
  } else if (b < 4864) {  // transpose+cast W (512x1536) -> BT (1536x512)
    int blk = b - 4096;
    int bk = blk & 15, bn = blk >> 4;
    int x = tid & 31, y = tid >> 5;
#pragma unroll
    for (int j = 0; j < 4; j++) {
      int r = y + j * 8;
      tile[r][x] = W[(size_t)(bk * 32 + r) * QKV_COLS + bn * 32 + x];
    }
    __syncthreads();
#pragma unroll
    for (int j = 0; j < 4; j++) {
      int r = y + j * 8;
      BT[(size_t)(bn * 32 + r) * CIN + bk * 32 + x] = (__bf16)tile[x][r];
    }
  } else if (b < 5152) {  // cast qt/kt tables -> [h][ab][d] bf16
    int i = (b - 4864) * 256 + tid;
    int d = i & 63, h = (i >> 6) & 7, ab = i >> 9;
    int po = (h * 144 + ab) * 64 + d;
    qtb[po] = (__bf16)qt[i];
    ktb[po] = (__bf16)kt[i];
  } else if (b < 5472) {  // vtT[h][d][p] bf16, p in [0,160), zero-padded past 144
    int i = (b - 5152) * 256 + tid;  // 8*64*160 = 81920
    int p = i % 160;
    int d = (i / 160) & 63;
    int h = i / 10240;
    vtT[i] = (p < 144) ? (__bf16)vt[p * 512 + h * 64 + d] : (__bf16)0.f;
  } else {  // edge setup
    int m = (b - 5472) * 256 + tid;
    int qi = pairs[m], ki = pairs[M_EDGES + m];
    unsigned pb = 0;
#pragma unroll
    for (int a = 0; a < 3; a++) {
      float rel = (xc[qi * 3 + a] - xc[ki * 3 + a]) / 0.05f + 24.0f;
      int bb = (int)rel;
      bb = bb < 0 ? 0 : (bb > 47 ? 47 : bb);
      pb |= (unsigned)bb << (6 * a);
    }
    qi_a[m] = qi;
    pack0[m] = (unsigned)ki | (pb << 13);
    atomicAdd(&cnt[qi], 1);
  }
}

// ---- bf16 MFMA GEMM, 64x128 tile, BK=64, XOR-swizzled LDS, double-buffered.
// grid = (bn=12, bm=128): consecutive blocks share one A tile (A streamed once). ----
__global__ __launch_bounds__(256) void gemm_qkv(const __bf16* __restrict__ A,
                                                const __bf16* __restrict__ BT,
                                                const float* __restrict__ bias,
                                                __bf16* __restrict__ qb,
                                                __bf16* __restrict__ kb,
                                                __bf16* __restrict__ vb) {
  __shared__ __align__(16) char At[2][64 * 128];   // 2x8KB
  __shared__ __align__(16) char Bt[2][128 * 128];  // 2x16KB
  int tid = threadIdx.x;
  int w = tid >> 6, l = tid & 63;
  int bn = blockIdx.x, bm = blockIdx.y;
  int wm = w & 1, wn = w >> 1;
  f32x4 acc[2][4] = {};
  const char* Ab = (const char*)A;
  const char* Bb = (const char*)BT;
  int lr = l & 15;
  int lk = (l >> 4) * 16;
  int xr = (lr & 7) << 4;

  auto stage = [&](int tk, int buf) {
#pragma unroll
    for (int r = 0; r < 2; r++) {
      int flat = r * 4096 + tid * 16;
      int row = flat >> 7, colb = flat & 127;
      int gcolb = colb ^ ((row & 7) << 4);
      gload_lds16(Ab + ((size_t)(bm * 64 + row) * CIN + tk * 64) * 2 + gcolb,
                  At[buf] + r * 4096 + w * 1024);
    }
#pragma unroll
    for (int r = 0; r < 4; r++) {
      int flat = r * 4096 + tid * 16;
      int row = flat >> 7, colb = flat & 127;
      int gcolb = colb ^ ((row & 7) << 4);
      gload_lds16(Bb + ((size_t)(bn * 128 + row) * CIN + tk * 64) * 2 + gcolb,
                  Bt[buf] + r * 4096 + w * 1024);
    }
  };

  stage(0, 0);
  __syncthreads();
  int cur = 0;
  for (int kt = 0; kt < 8; kt++) {
    if (kt < 7) stage(kt + 1, cur ^ 1);  // prefetch next tile; drained by barrier below
#pragma unroll
    for (int ks = 0; ks < 2; ks++) {
      bf16x8 af[2], bfr[4];
      int cs = (ks * 64 + lk) ^ xr;
#pragma unroll
      for (int mf = 0; mf < 2; mf++) af[mf] = *(const bf16x8*)(At[cur] + (wm * 32 + mf * 16 + lr) * 128 + cs);
#pragma unroll
      for (int nf = 0; nf < 4; nf++) bfr[nf] = *(const bf16x8*)(Bt[cur] + (wn * 64 + nf * 16 + lr) * 128 + cs);
#pragma unroll
      for (int mf = 0; mf < 2; mf++)
#pragma unroll
        for (int nf = 0; nf < 4; nf++)
          acc[mf][nf] = __builtin_amdgcn_mfma_f32_16x16x32_bf16(af[mf], bfr[nf], acc[mf][nf], 0, 0, 0);
    }
    __syncthreads();
    cur ^= 1;
  }

  int lg = l >> 4;
#pragma unroll
  for (int mf = 0; mf < 2; mf++) {
#pragma unroll
    for (int nf = 0; nf < 4; nf++) {
      int gc = bn * 128 + wn * 64 + nf * 16 + lr;
      float b = bias[gc];
      int which = gc >> 9;
      int col = gc & 511;
      __bf16* dst = which == 0 ? qb : (which == 1 ? kb : vb);
      float scale = which == 0 ? 0.125f : 1.0f;
#pragma unroll
      for (int j = 0; j < 4; j++) {
        int gr = bm * 64 + wm * 32 + mf * 16 + lg * 4 + j;
        dst[(size_t)gr * 512 + col] = (__bf16)((acc[mf][nf][j] + b) * scale);
      }
    }
  }
}

// ---- table_dot (q and k via z): out[n][ab*8+h] = src[n,h,:] . tab[h,ab,:] ----
__global__ __launch_bounds__(256) void table_dot(const __bf16* __restrict__ qb,
                                                 const __bf16* __restrict__ kb,
                                                 const __bf16* __restrict__ qtb,
                                                 const __bf16* __restrict__ ktb,
                                                 __bf16* __restrict__ qdot,
                                                 __bf16* __restrict__ kdot) {
  __shared__ __align__(16) char As[128 * 128];
  __shared__ __align__(16) char Bs[144 * 128];
  int nt = blockIdx.x, h = blockIdx.y, z = blockIdx.z;
  const __bf16* src = z ? kb : qb;
  const __bf16* tab = z ? ktb : qtb;
  __bf16* out = z ? kdot : qdot;
  int tid = threadIdx.x, w = tid >> 6, l = tid & 63;
  const char* sb = (const char*)src;
  const char* tb = (const char*)tab + (size_t)h * 144 * 128;
#pragma unroll
  for (int p = 0; p < 4; p++) {
    int flat = p * 4096 + tid * 16;
    int row = flat >> 7, colb = flat & 127;
    int gcolb = colb ^ ((row & 7) << 4);
    gload_lds16(sb + (size_t)(nt * 128 + row) * 1024 + h * 128 + gcolb, As + p * 4096 + w * 1024);
    gload_lds16(tb + row * 128 + gcolb, Bs + p * 4096 + w * 1024);
  }
  if (w < 2) {
    int flat = 16384 + w * 1024 + l * 16;
    int row = flat >> 7, colb = flat & 127;
    int gcolb = colb ^ ((row & 7) << 4);
    gload_lds16(tb + row * 128 + gcolb, Bs + 16384 + w * 1024);
  }
  __syncthreads();

  f32x4 acc[2][9] = {};
  int lr = l & 15, lk = (l >> 4) * 16;
  int xr = (lr & 7) << 4;
#pragma unroll
  for (int ks = 0; ks < 2; ks++) {
    bf16x8 af[2], bf[9];
    int cs = (ks * 64 + lk) ^ xr;
#pragma unroll
    for (int mf = 0; mf < 2; mf++)
      af[mf] = *(const bf16x8*)(As + (w * 32 + mf * 16 + lr) * 128 + cs);
#pragma unroll
    for (int nf = 0; nf < 9; nf++)
      bf[nf] = *(const bf16x8*)(Bs + (nf * 16 + lr) * 128 + cs);
#pragma unroll
    for (int mf = 0; mf < 2; mf++)
#pragma unroll
      for (int nf = 0; nf < 9; nf++)
        acc[mf][nf] = __builtin_amdgcn_mfma_f32_16x16x32_bf16(af[mf], bf[nf], acc[mf][nf], 0, 0, 0);
  }

  int lg = l >> 4;
#pragma unroll
  for (int mf = 0; mf < 2; mf++)
#pragma unroll
    for (int nf = 0; nf < 9; nf++)
#pragma unroll
      for (int j = 0; j < 4; j++) {
        int n = nt * 128 + w * 32 + mf * 16 + lg * 4 + j;
        int ab = nf * 16 + lr;
        out[(size_t)n * 1152 + ab * 8 + h] = (__bf16)acc[mf][nf][j];
      }
}

// ---- scan: 256 threads, 32 counts each ----
__global__ __launch_bounds__(256) void scan_kernel(const int* __restrict__ cnt,
                                                   int* __restrict__ off,
                                                   int* __restrict__ cursor) {
  __shared__ int wsum[4];
  int tid = threadIdx.x, lane = tid & 63, w = tid >> 6;
  int local[32];
  int s = 0;
#pragma unroll
  for (int i = 0; i < 8; i++) {
    int4 v = ((const int4*)cnt)[tid * 8 + i];
    local[i * 4 + 0] = v.x; local[i * 4 + 1] = v.y;
    local[i * 4 + 2] = v.z; local[i * 4 + 3] = v.w;
    s += v.x + v.y + v.z + v.w;
  }
  int incl = s;
#pragma unroll
  for (int d = 1; d < 64; d <<= 1) {
    int t = __shfl_up(incl, d, 64);
    if (lane >= d) incl += t;
  }
  if (lane == 63) wsum[w] = incl;
  __syncthreads();
  int woff = 0;
#pragma unroll
  for (int j = 0; j < 4; j++) woff += (j < w) ? wsum[j] : 0;
  int run = woff + incl - s;
  int base = tid * 32;
#pragma unroll
  for (int i = 0; i < 32; i++) {
    off[base + i] = run;
    cursor[base + i] = run;
    run += local[i];
  }
  if (tid == 255) off[N_PTS] = run;
}

// ---- scatter edges into CSR order ----
__global__ void scatter_k(const int* __restrict__ qi_a, const unsigned* __restrict__ pack0,
                          int* __restrict__ cursor, unsigned* __restrict__ epack) {
  int m = blockIdx.x * blockDim.x + threadIdx.x;
  if (m < M_EDGES) {
    int qi = qi_a[m];
    int pos = atomicAdd(&cursor[qi], 1);
    epack[pos] = pack0[m];
  }
}

// ---- fused attention: block=query, wave=head (R5 structure). Table bias folded in:
// lane dg in 0..5 gathers one bf16 from qdot[n] (dg<3) / kdot[ki] (dg>=3) and adds it
// to its partial before the 8-lane shfl reduce. Writes num (into out), den, Hb. ----
__global__ __launch_bounds__(512) void attn_kernel(
    const __bf16* __restrict__ qb, const __bf16* __restrict__ kb,
    const __bf16* __restrict__ vb, const __bf16* __restrict__ qdot,
    const __bf16* __restrict__ kdot, const int* __restrict__ off,
    const unsigned* __restrict__ epack,
    float* __restrict__ num, float* __restrict__ den, __bf16* __restrict__ Hb) {
  __shared__ float hist[8 * 160];
  int n = blockIdx.x;
  int tid = threadIdx.x;
  int h = tid >> 6, l = tid & 63;
  int es = l >> 3, dg = l & 7;
  int tcol = h * 64 + dg * 8;

  for (int i = tid; i < 1280; i += 512) hist[i] = 0.f;
  __syncthreads();

  bf16x8 q8 = *(const bf16x8*)(qb + (n << 9) + tcol);
  float qv[8];
#pragma unroll
  for (int j = 0; j < 8; j++) qv[j] = (float)q8[j];

  float acc[8] = {0.f, 0.f, 0.f, 0.f, 0.f, 0.f, 0.f, 0.f};
  float dn = 0.f;
  int e0 = off[n], e1 = off[n + 1];
  const __bf16* qd_row = qdot + (size_t)n * 1152;
  int axis = dg < 3 ? dg : dg - 3;     // table axis handled by this lane
  int tsh = 6 * axis;

  for (int base = e0; base < e1; base += 8) {
    int e = base + es;
    bool valid = e < e1;
    int ee = valid ? e : e0;
    unsigned pk = epack[ee];
    int ki = pk & 8191;
    unsigned pb = pk >> 13;
    bf16x8 k8 = *(const bf16x8*)(kb + (ki << 9) + tcol);
    bf16x8 v8 = *(const bf16x8*)(vb + (ki << 9) + tcol);
    // folded edge-bias gather (was edge_bias kernel): 6 of 8 dg-lanes, 1 bf16 each
    int bin = (int)((pb >> tsh) & 63u);
    int idx = (axis * 48 + bin) * 8 + h;
    const __bf16* tbl = dg < 3 ? qd_row : (kdot + (size_t)ki * 1152);
    float p = (dg < 6) ? (float)tbl[idx] : 0.f;
#pragma unroll
    for (int j = 0; j < 8; j++) p += qv[j] * (float)k8[j];
    p += __shfl_xor(p, 1, 64);
    p += __shfl_xor(p, 2, 64);
    p += __shfl_xor(p, 4, 64);
    float x = valid ? __expf(p) : 0.f;
    dn += x;
#pragma unroll
    for (int j = 0; j < 8; j++) acc[j] += x * (float)v8[j];
    if (dg == 0 && valid) {
      float* hh = hist + h * 160;
      atomicAdd(hh + (pb & 63), x);
      atomicAdd(hh + 48 + ((pb >> 6) & 63), x);
      atomicAdd(hh + 96 + ((pb >> 12) & 63), x);
    }
  }

#pragma unroll
  for (int s = 8; s <= 32; s <<= 1) {
    dn += __shfl_xor(dn, s, 64);
#pragma unroll
    for (int j = 0; j < 8; j++) acc[j] += __shfl_xor(acc[j], s, 64);
  }

  if (l < 8) {
    float* op = num + (n << 9) + h * 64 + l * 8;
    f32x4 o0 = {acc[0], acc[1], acc[2], acc[3]};
    f32x4 o1 = {acc[4], acc[5], acc[6], acc[7]};
    *(f32x4*)op = o0;
    *(f32x4*)(op + 4) = o1;
  }
  if (l == 0) den[n * 8 + h] = dn;
  __syncthreads();
  for (int i = tid; i < 1280; i += 512) Hb[(size_t)n * 1280 + i] = (__bf16)hist[i];
}

// ---- finish: out = (num + Hb @ vtT) * invden.  Per block: 128 queries x 1 head. ----
__global__ __launch_bounds__(256) void finish_kernel(const __bf16* __restrict__ Hb,
                                                     const __bf16* __restrict__ vtT,
                                                     const float* __restrict__ den,
                                                     float* __restrict__ out) {
  __shared__ __align__(16) char As[2][128 * 64];  // 2x8KB
  __shared__ __align__(16) char Bs[2][64 * 64];   // 2x4KB
  int nt = blockIdx.x, h = blockIdx.y;
  int tid = threadIdx.x, w = tid >> 6, l = tid & 63;
  int lr = l & 15, lk = (l >> 4) * 16;
  int xr = (lr & 3) << 4;
  const char* Ab = (const char*)Hb;
  const char* Bb = (const char*)vtT;
  f32x4 acc[2][4] = {};

  auto stage = [&](int tk, int buf) {
#pragma unroll
    for (int c = 0; c < 2; c++) {
      int flat = c * 4096 + tid * 16;
      int row = flat >> 6, colb = flat & 63;
      int gcolb = colb ^ ((row & 3) << 4);
      gload_lds16(Ab + ((size_t)(nt * 128 + row) * 1280 + h * 160 + tk * 32) * 2 + gcolb,
                  As[buf] + c * 4096 + w * 1024);
    }
    {
      int flat = tid * 16;
      int row = flat >> 6, colb = flat & 63;
      int gcolb = colb ^ ((row & 3) << 4);
      gload_lds16(Bb + ((size_t)(h * 64 + row) * 160 + tk * 32) * 2 + gcolb,
                  Bs[buf] + w * 1024);
    }
  };

  stage(0, 0);
  __syncthreads();
  int cur = 0;
  for (int kt = 0; kt < 5; kt++) {
    if (kt < 4) stage(kt + 1, cur ^ 1);
    bf16x8 af[2], bf[4];
    int cs = lk ^ xr;
#pragma unroll
    for (int mf = 0; mf < 2; mf++) af[mf] = *(const bf16x8*)(As[cur] + (w * 32 + mf * 16 + lr) * 64 + cs);
#pragma unroll
    for (int nf = 0; nf < 4; nf++) bf[nf] = *(const bf16x8*)(Bs[cur] + (nf * 16 + lr) * 64 + cs);
#pragma unroll
    for (int mf = 0; mf < 2; mf++)
#pragma unroll
      for (int nf = 0; nf < 4; nf++)
        acc[mf][nf] = __builtin_amdgcn_mfma_f32_16x16x32_bf16(af[mf], bf[nf], acc[mf][nf], 0, 0, 0);
    __syncthreads();
    cur ^= 1;
  }

  int lg = l >> 4;
#pragma unroll
  for (int mf = 0; mf < 2; mf++) {
#pragma unroll
    for (int j = 0; j < 4; j++) {
      int n = nt * 128 + w * 32 + mf * 16 + lg * 4 + j;
      float dnv = den[n * 8 + h];
      float inv = dnv > 0.f ? 1.f / dnv : 0.f;
#pragma unroll
      for (int nf = 0; nf < 4; nf++) {
        int gi = (n << 9) + h * 64 + nf * 16 + lr;
        out[gi] = (out[gi] + acc[mf][nf][j]) * inv;
      }
    }
  }
}

extern "C" void kernel_launch(void* const* d_in, const int* in_sizes, int n_in,
                              void* d_out, int out_size, void* d_ws, size_t ws_size,
                              hipStream_t stream) {
  const float* xF = (const float*)d_in[0];
  const float* xC = (const float*)d_in[1];
  const int* pairs = (const int*)d_in[2];
  const float* W = (const float*)d_in[3];
  const float* bias = (const float*)d_in[4];
  const float* qt = (const float*)d_in[5];
  const float* kt = (const float*)d_in[6];
  const float* vt = (const float*)d_in[7];
  float* out = (float*)d_out;

  char* ws = (char*)d_ws;
  size_t o = 0;
  auto alloc = [&](size_t bytes) {
    void* p = ws + o;
    o = (o + bytes + 255) & ~(size_t)255;
    return p;
  };
  // region 0: A+BT live only until gemm_qkv; Hb (written by attn, later) aliases them.
  char* region0 = (char*)alloc((size_t)N_PTS * 1280 * 2);  // 20.97 MB
  __bf16* A = (__bf16*)region0;                      // 8 MB
  __bf16* BT = (__bf16*)(region0 + (size_t)N_PTS * CIN * 2);  // 1.5 MB
  __bf16* Hb = (__bf16*)region0;                     // aliases A/BT after gemm
  __bf16* qb = (__bf16*)alloc((size_t)N_PTS * 512 * 2);
  __bf16* kb = (__bf16*)alloc((size_t)N_PTS * 512 * 2);
  __bf16* vb = (__bf16*)alloc((size_t)N_PTS * 512 * 2);
  __bf16* qtb = (__bf16*)alloc((size_t)8 * 144 * 64 * 2);
  __bf16* ktb = (__bf16*)alloc((size_t)8 * 144 * 64 * 2);
  __bf16* vtT = (__bf16*)alloc((size_t)8 * 64 * 160 * 2);
  __bf16* qdot = (__bf16*)alloc((size_t)N_PTS * 1152 * 2);
  __bf16* kdot = (__bf16*)alloc((size_t)N_PTS * 1152 * 2);
  float* den = (float*)alloc((size_t)N_PTS * 8 * 4);
  int* qi_a = (int*)alloc(M_EDGES * 4);
  unsigned* pack0 = (unsigned*)alloc(M_EDGES * 4);
  unsigned* epack = (unsigned*)alloc(M_EDGES * 4);
  int* cnt = (int*)alloc(N_PTS * 4);
  int* off = (int*)alloc((N_PTS + 1) * 4);
  int* cursor = (int*)alloc(N_PTS * 4);

  hipMemsetAsync(cnt, 0, N_PTS * 4, stream);

  prep_kernel<<<5984, 256, 0, stream>>>(xF, W, qt, kt, vt, pairs, xC,
                                        A, BT, qtb, ktb, vtT, qi_a, pack0, cnt);
  scan_kernel<<<1, 256, 0, stream>>>(cnt, off, cursor);
  scatter_k<<<M_EDGES / 256, 256, 0, stream>>>(qi_a, pack0, cursor, epack);
  gemm_qkv<<<dim3(QKV_COLS / 128, N_PTS / 64), 256, 0, stream>>>(A, BT, bias, qb, kb, vb);
  table_dot<<<dim3(N_PTS / 128, 8, 2), 256, 0, stream>>>(qb, kb, qtb, ktb, qdot, kdot);
  attn_kernel<<<N_PTS, 512, 0, stream>>>(qb, kb, vb, qdot, kdot, off, epack, out, den, Hb);
  finish_kernel<<<dim3(N_PTS / 128, 8), 256, 0, stream>>>(Hb, vtT, den, out);
}

// Round 8
// 156.831 us; speedup vs baseline: 1.1468x; 1.0515x over previous
//
#include <hip/hip_runtime.h>
#include <hip/hip_bf16.h>
#include <stdint.h>

#define N_PTS 8192
#define M_EDGES 131072
#define CIN 512
#define QKV_COLS 1536

typedef __bf16 bf16x8 __attribute__((ext_vector_type(8)));
typedef float f32x4 __attribute__((ext_vector_type(4)));

#define GAS __attribute__((address_space(1)))
#define LAS __attribute__((address_space(3)))

__device__ __forceinline__ void gload_lds16(const void* g, void* l) {
  __builtin_amdgcn_global_load_lds((const GAS void*)g, (LAS void*)l, 16, 0, 0);
}

// ---- prep: cast_a | cast_bt | cast qk-tables | build vtT | edge_setup, one launch ----
__global__ __launch_bounds__(256) void prep_kernel(
    const float* __restrict__ xF, const float* __restrict__ W,
    const float* __restrict__ qt, const float* __restrict__ kt,
    const float* __restrict__ vt, const int* __restrict__ pairs,
    const float* __restrict__ xc,
    __bf16* __restrict__ A, __bf16* __restrict__ BT,
    __bf16* __restrict__ qtb, __bf16* __restrict__ ktb, __bf16* __restrict__ vtT,
    int* __restrict__ qi_a, unsigned* __restrict__ pack0, int* __restrict__ cnt) {
  __shared__ float tile[32][33];
  int b = blockIdx.x;
  int tid = threadIdx.x;
  if (b < 4096) {  // cast x_F -> bf16 A
    int base = (b * 256 + tid) * 4;
    float4 v = *(const float4*)(xF + base);
    A[base + 0] = (__bf16)v.x;
    A[base + 1] = (__bf16)v.y;
    A[base + 2] = (__bf16)v.z;
    A[base + 3] = (__bf16)v.w;
  } else if (b < 4864) {  // transpose+cast W (512x1536) -> BT (1536x512)
    int blk = b - 4096;
    int bk = blk & 15, bn = blk >> 4;
    int x = tid & 31, y = tid >> 5;
#pragma unroll
    for (int j = 0; j < 4; j++) {
      int r = y + j * 8;
      tile[r][x] = W[(size_t)(bk * 32 + r) * QKV_COLS + bn * 32 + x];
    }
    __syncthreads();
#pragma unroll
    for (int j = 0; j < 4; j++) {
      int r = y + j * 8;
      BT[(size_t)(bn * 32 + r) * CIN + bk * 32 + x] = (__bf16)tile[x][r];
    }
  } else if (b < 5152) {  // cast qt/kt tables -> [h][ab][d] bf16
    int i = (b - 4864) * 256 + tid;
    int d = i & 63, h = (i >> 6) & 7, ab = i >> 9;
    int po = (h * 144 + ab) * 64 + d;
    qtb[po] = (__bf16)qt[i];
    ktb[po] = (__bf16)kt[i];
  } else if (b < 5472) {  // vtT[h][d][p] bf16, p in [0,160), zero-padded past 144
    int i = (b - 5152) * 256 + tid;  // 8*64*160 = 81920
    int p = i % 160;
    int d = (i / 160) & 63;
    int h = i / 10240;
    vtT[i] = (p < 144) ? (__bf16)vt[p * 512 + h * 64 + d] : (__bf16)0.f;
  } else {  // edge setup
    int m = (b - 5472) * 256 + tid;
    int qi = pairs[m], ki = pairs[M_EDGES + m];
    unsigned pb = 0;
#pragma unroll
    for (int a = 0; a < 3; a++) {
      float rel = (xc[qi * 3 + a] - xc[ki * 3 + a]) / 0.05f + 24.0f;
      int bb = (int)rel;
      bb = bb < 0 ? 0 : (bb > 47 ? 47 : bb);
      pb |= (unsigned)bb << (6 * a);
    }
    qi_a[m] = qi;
    pack0[m] = (unsigned)ki | (pb << 13);
    atomicAdd(&cnt[qi], 1);
  }
}

// ---- bf16 MFMA GEMM, 64x128 tile, BK=64, XOR-swizzled LDS, double-buffered. ----
__global__ __launch_bounds__(256) void gemm_qkv(const __bf16* __restrict__ A,
                                                const __bf16* __restrict__ BT,
                                                const float* __restrict__ bias,
                                                __bf16* __restrict__ qb,
                                                __bf16* __restrict__ kb,
                                                __bf16* __restrict__ vb) {
  __shared__ __align__(16) char At[2][64 * 128];   // 2x8KB
  __shared__ __align__(16) char Bt[2][128 * 128];  // 2x16KB
  int tid = threadIdx.x;
  int w = tid >> 6, l = tid & 63;
  int bn = blockIdx.x, bm = blockIdx.y;
  int wm = w & 1, wn = w >> 1;
  f32x4 acc[2][4] = {};
  const char* Ab = (const char*)A;
  const char* Bb = (const char*)BT;
  int lr = l & 15;
  int lk = (l >> 4) * 16;
  int xr = (lr & 7) << 4;

  auto stage = [&](int tk, int buf) {
#pragma unroll
    for (int r = 0; r < 2; r++) {
      int flat = r * 4096 + tid * 16;
      int row = flat >> 7, colb = flat & 127;
      int gcolb = colb ^ ((row & 7) << 4);
      gload_lds16(Ab + ((size_t)(bm * 64 + row) * CIN + tk * 64) * 2 + gcolb,
                  At[buf] + r * 4096 + w * 1024);
    }
#pragma unroll
    for (int r = 0; r < 4; r++) {
      int flat = r * 4096 + tid * 16;
      int row = flat >> 7, colb = flat & 127;
      int gcolb = colb ^ ((row & 7) << 4);
      gload_lds16(Bb + ((size_t)(bn * 128 + row) * CIN + tk * 64) * 2 + gcolb,
                  Bt[buf] + r * 4096 + w * 1024);
    }
  };

  stage(0, 0);
  __syncthreads();
  int cur = 0;
  for (int kt = 0; kt < 8; kt++) {
    if (kt < 7) stage(kt + 1, cur ^ 1);  // prefetch next tile; drained by barrier below
#pragma unroll
    for (int ks = 0; ks < 2; ks++) {
      bf16x8 af[2], bfr[4];
      int cs = (ks * 64 + lk) ^ xr;
#pragma unroll
      for (int mf = 0; mf < 2; mf++) af[mf] = *(const bf16x8*)(At[cur] + (wm * 32 + mf * 16 + lr) * 128 + cs);
#pragma unroll
      for (int nf = 0; nf < 4; nf++) bfr[nf] = *(const bf16x8*)(Bt[cur] + (wn * 64 + nf * 16 + lr) * 128 + cs);
#pragma unroll
      for (int mf = 0; mf < 2; mf++)
#pragma unroll
        for (int nf = 0; nf < 4; nf++)
          acc[mf][nf] = __builtin_amdgcn_mfma_f32_16x16x32_bf16(af[mf], bfr[nf], acc[mf][nf], 0, 0, 0);
    }
    __syncthreads();
    cur ^= 1;
  }

  int lg = l >> 4;
#pragma unroll
  for (int mf = 0; mf < 2; mf++) {
#pragma unroll
    for (int nf = 0; nf < 4; nf++) {
      int gc = bn * 128 + wn * 64 + nf * 16 + lr;
      float b = bias[gc];
      int which = gc >> 9;
      int col = gc & 511;
      __bf16* dst = which == 0 ? qb : (which == 1 ? kb : vb);
      float scale = which == 0 ? 0.125f : 1.0f;
#pragma unroll
      for (int j = 0; j < 4; j++) {
        int gr = bm * 64 + wm * 32 + mf * 16 + lg * 4 + j;
        dst[(size_t)gr * 512 + col] = (__bf16)((acc[mf][nf][j] + b) * scale);
      }
    }
  }
}

// ---- table_dot (q and k via z): out[n][ab*8+h] = src[n,h,:] . tab[h,ab,:] ----
__global__ __launch_bounds__(256) void table_dot(const __bf16* __restrict__ qb,
                                                 const __bf16* __restrict__ kb,
                                                 const __bf16* __restrict__ qtb,
                                                 const __bf16* __restrict__ ktb,
                                                 __bf16* __restrict__ qdot,
                                                 __bf16* __restrict__ kdot) {
  __shared__ __align__(16) char As[128 * 128];
  __shared__ __align__(16) char Bs[144 * 128];
  int nt = blockIdx.x, h = blockIdx.y, z = blockIdx.z;
  const __bf16* src = z ? kb : qb;
  const __bf16* tab = z ? ktb : qtb;
  __bf16* out = z ? kdot : qdot;
  int tid = threadIdx.x, w = tid >> 6, l = tid & 63;
  const char* sb = (const char*)src;
  const char* tb = (const char*)tab + (size_t)h * 144 * 128;
#pragma unroll
  for (int p = 0; p < 4; p++) {
    int flat = p * 4096 + tid * 16;
    int row = flat >> 7, colb = flat & 127;
    int gcolb = colb ^ ((row & 7) << 4);
    gload_lds16(sb + (size_t)(nt * 128 + row) * 1024 + h * 128 + gcolb, As + p * 4096 + w * 1024);
    gload_lds16(tb + row * 128 + gcolb, Bs + p * 4096 + w * 1024);
  }
  if (w < 2) {
    int flat = 16384 + w * 1024 + l * 16;
    int row = flat >> 7, colb = flat & 127;
    int gcolb = colb ^ ((row & 7) << 4);
    gload_lds16(tb + row * 128 + gcolb, Bs + 16384 + w * 1024);
  }
  __syncthreads();

  f32x4 acc[2][9] = {};
  int lr = l & 15, lk = (l >> 4) * 16;
  int xr = (lr & 7) << 4;
#pragma unroll
  for (int ks = 0; ks < 2; ks++) {
    bf16x8 af[2], bf[9];
    int cs = (ks * 64 + lk) ^ xr;
#pragma unroll
    for (int mf = 0; mf < 2; mf++)
      af[mf] = *(const bf16x8*)(As + (w * 32 + mf * 16 + lr) * 128 + cs);
#pragma unroll
    for (int nf = 0; nf < 9; nf++)
      bf[nf] = *(const bf16x8*)(Bs + (nf * 16 + lr) * 128 + cs);
#pragma unroll
    for (int mf = 0; mf < 2; mf++)
#pragma unroll
      for (int nf = 0; nf < 9; nf++)
        acc[mf][nf] = __builtin_amdgcn_mfma_f32_16x16x32_bf16(af[mf], bf[nf], acc[mf][nf], 0, 0, 0);
  }

  int lg = l >> 4;
#pragma unroll
  for (int mf = 0; mf < 2; mf++)
#pragma unroll
    for (int nf = 0; nf < 9; nf++)
#pragma unroll
      for (int j = 0; j < 4; j++) {
        int n = nt * 128 + w * 32 + mf * 16 + lg * 4 + j;
        int ab = nf * 16 + lr;
        out[(size_t)n * 1152 + ab * 8 + h] = (__bf16)acc[mf][nf][j];
      }
}

// ---- scan: 256 threads, 32 counts each ----
__global__ __launch_bounds__(256) void scan_kernel(const int* __restrict__ cnt,
                                                   int* __restrict__ off,
                                                   int* __restrict__ cursor) {
  __shared__ int wsum[4];
  int tid = threadIdx.x, lane = tid & 63, w = tid >> 6;
  int local[32];
  int s = 0;
#pragma unroll
  for (int i = 0; i < 8; i++) {
    int4 v = ((const int4*)cnt)[tid * 8 + i];
    local[i * 4 + 0] = v.x; local[i * 4 + 1] = v.y;
    local[i * 4 + 2] = v.z; local[i * 4 + 3] = v.w;
    s += v.x + v.y + v.z + v.w;
  }
  int incl = s;
#pragma unroll
  for (int d = 1; d < 64; d <<= 1) {
    int t = __shfl_up(incl, d, 64);
    if (lane >= d) incl += t;
  }
  if (lane == 63) wsum[w] = incl;
  __syncthreads();
  int woff = 0;
#pragma unroll
  for (int j = 0; j < 4; j++) woff += (j < w) ? wsum[j] : 0;
  int run = woff + incl - s;
  int base = tid * 32;
#pragma unroll
  for (int i = 0; i < 32; i++) {
    off[base + i] = run;
    cursor[base + i] = run;
    run += local[i];
  }
  if (tid == 255) off[N_PTS] = run;
}

// ---- scatter edges into CSR order ----
__global__ void scatter_k(const int* __restrict__ qi_a, const unsigned* __restrict__ pack0,
                          int* __restrict__ cursor, unsigned* __restrict__ epack) {
  int m = blockIdx.x * blockDim.x + threadIdx.x;
  if (m < M_EDGES) {
    int qi = qi_a[m];
    int pos = atomicAdd(&cursor[qi], 1);
    epack[pos] = pack0[m];
  }
}

// ---- fused attention: block=query; WAVE = edge-slot, lanes = 8 heads x 8 dim-groups.
// Each wave privately walks edges e0+w, e0+w+8, ...; full k/v rows coalesced per wave.
// Cross-wave num/den reduce via LDS. Writes num (into out), den, Hb. ----
__global__ __launch_bounds__(512) void attn_kernel(
    const __bf16* __restrict__ qb, const __bf16* __restrict__ kb,
    const __bf16* __restrict__ vb, const __bf16* __restrict__ qdot,
    const __bf16* __restrict__ kdot, const int* __restrict__ off,
    const unsigned* __restrict__ epack,
    float* __restrict__ num, float* __restrict__ den, __bf16* __restrict__ Hb) {
  __shared__ float hist[8 * 164];   // rows padded 160->164 (breaks 8-way bank conflict)
  __shared__ float part[8][512];    // per-wave num partials
  __shared__ float dpart[8][8];     // per-wave den partials
  int n = blockIdx.x;
  int tid = threadIdx.x;
  int w = tid >> 6, l = tid & 63;
  int h = l >> 3, dg = l & 7;       // lane = (head, dim-group)

  for (int i = tid; i < 8 * 164; i += 512) hist[i] = 0.f;
  __syncthreads();

  bf16x8 q8 = *(const bf16x8*)(qb + (n << 9) + l * 8);
  float qv[8];
#pragma unroll
  for (int j = 0; j < 8; j++) qv[j] = (float)q8[j];

  float acc[8] = {0.f, 0.f, 0.f, 0.f, 0.f, 0.f, 0.f, 0.f};
  float dn = 0.f;
  int e0 = off[n], e1 = off[n + 1];
  const __bf16* qd_row = qdot + (size_t)n * 1152;
  int axis = dg < 3 ? dg : dg - 3;
  int tsh = 6 * axis;

  for (int e = e0 + w; e < e1; e += 8) {
    unsigned pk = epack[__builtin_amdgcn_readfirstlane(e)];  // wave-uniform s_load
    int ki = pk & 8191;
    unsigned pb = pk >> 13;
    bf16x8 k8 = *(const bf16x8*)(kb + (ki << 9) + l * 8);   // full row, coalesced
    bf16x8 v8 = *(const bf16x8*)(vb + (ki << 9) + l * 8);
    int bin = (int)((pb >> tsh) & 63u);
    int idx = (axis * 48 + bin) * 8 + h;
    const __bf16* tbl = dg < 3 ? qd_row : (kdot + (size_t)ki * 1152);
    float p = (dg < 6) ? (float)tbl[idx] : 0.f;
#pragma unroll
    for (int j = 0; j < 8; j++) p += qv[j] * (float)k8[j];
    p += __shfl_xor(p, 1, 64);
    p += __shfl_xor(p, 2, 64);
    p += __shfl_xor(p, 4, 64);   // now p = full logit for (edge e, head h)
    float x = __expf(p);
    dn += x;
#pragma unroll
    for (int j = 0; j < 8; j++) acc[j] += x * (float)v8[j];
    if (dg == 0) {               // 8 lanes (one per head) in parallel
      float* hh = hist + h * 164;
      atomicAdd(hh + (pb & 63), x);
      atomicAdd(hh + 48 + ((pb >> 6) & 63), x);
      atomicAdd(hh + 96 + ((pb >> 12) & 63), x);
    }
  }

  // per-wave partials -> LDS, then cross-wave reduce
  f32x4 a0 = {acc[0], acc[1], acc[2], acc[3]};
  f32x4 a1 = {acc[4], acc[5], acc[6], acc[7]};
  *(f32x4*)&part[w][l * 8] = a0;
  *(f32x4*)&part[w][l * 8 + 4] = a1;
  if (dg == 0) dpart[w][h] = dn;
  __syncthreads();

  float s = 0.f;
#pragma unroll
  for (int ww = 0; ww < 8; ww++) s += part[ww][tid];
  num[(n << 9) + tid] = s;
  if (tid < 8) {
    float d = 0.f;
#pragma unroll
    for (int ww = 0; ww < 8; ww++) d += dpart[ww][tid];
    den[n * 8 + tid] = d;
  }
  for (int i = tid; i < 1280; i += 512) {
    int hh = i / 160, p = i % 160;
    Hb[(size_t)n * 1280 + i] = (__bf16)hist[hh * 164 + p];
  }
}

// ---- finish: out = (num + Hb @ vtT) * invden.  Per block: 128 queries x 1 head. ----
__global__ __launch_bounds__(256) void finish_kernel(const __bf16* __restrict__ Hb,
                                                     const __bf16* __restrict__ vtT,
                                                     const float* __restrict__ den,
                                                     float* __restrict__ out) {
  __shared__ __align__(16) char As[2][128 * 64];  // 2x8KB
  __shared__ __align__(16) char Bs[2][64 * 64];   // 2x4KB
  int nt = blockIdx.x, h = blockIdx.y;
  int tid = threadIdx.x, w = tid >> 6, l = tid & 63;
  int lr = l & 15, lk = (l >> 4) * 16;
  int xr = (lr & 3) << 4;
  const char* Ab = (const char*)Hb;
  const char* Bb = (const char*)vtT;
  f32x4 acc[2][4] = {};

  auto stage = [&](int tk, int buf) {
#pragma unroll
    for (int c = 0; c < 2; c++) {
      int flat = c * 4096 + tid * 16;
      int row = flat >> 6, colb = flat & 63;
      int gcolb = colb ^ ((row & 3) << 4);
      gload_lds16(Ab + ((size_t)(nt * 128 + row) * 1280 + h * 160 + tk * 32) * 2 + gcolb,
                  As[buf] + c * 4096 + w * 1024);
    }
    {
      int flat = tid * 16;
      int row = flat >> 6, colb = flat & 63;
      int gcolb = colb ^ ((row & 3) << 4);
      gload_lds16(Bb + ((size_t)(h * 64 + row) * 160 + tk * 32) * 2 + gcolb,
                  Bs[buf] + w * 1024);
    }
  };

  stage(0, 0);
  __syncthreads();
  int cur = 0;
  for (int kt = 0; kt < 5; kt++) {
    if (kt < 4) stage(kt + 1, cur ^ 1);
    bf16x8 af[2], bf[4];
    int cs = lk ^ xr;
#pragma unroll
    for (int mf = 0; mf < 2; mf++) af[mf] = *(const bf16x8*)(As[cur] + (w * 32 + mf * 16 + lr) * 64 + cs);
#pragma unroll
    for (int nf = 0; nf < 4; nf++) bf[nf] = *(const bf16x8*)(Bs[cur] + (nf * 16 + lr) * 64 + cs);
#pragma unroll
    for (int mf = 0; mf < 2; mf++)
#pragma unroll
      for (int nf = 0; nf < 4; nf++)
        acc[mf][nf] = __builtin_amdgcn_mfma_f32_16x16x32_bf16(af[mf], bf[nf], acc[mf][nf], 0, 0, 0);
    __syncthreads();
    cur ^= 1;
  }

  int lg = l >> 4;
#pragma unroll
  for (int mf = 0; mf < 2; mf++) {
#pragma unroll
    for (int j = 0; j < 4; j++) {
      int n = nt * 128 + w * 32 + mf * 16 + lg * 4 + j;
      float dnv = den[n * 8 + h];
      float inv = dnv > 0.f ? 1.f / dnv : 0.f;
#pragma unroll
      for (int nf = 0; nf < 4; nf++) {
        int gi = (n << 9) + h * 64 + nf * 16 + lr;
        out[gi] = (out[gi] + acc[mf][nf][j]) * inv;
      }
    }
  }
}

extern "C" void kernel_launch(void* const* d_in, const int* in_sizes, int n_in,
                              void* d_out, int out_size, void* d_ws, size_t ws_size,
                              hipStream_t stream) {
  const float* xF = (const float*)d_in[0];
  const float* xC = (const float*)d_in[1];
  const int* pairs = (const int*)d_in[2];
  const float* W = (const float*)d_in[3];
  const float* bias = (const float*)d_in[4];
  const float* qt = (const float*)d_in[5];
  const float* kt = (const float*)d_in[6];
  const float* vt = (const float*)d_in[7];
  float* out = (float*)d_out;

  char* ws = (char*)d_ws;
  size_t o = 0;
  auto alloc = [&](size_t bytes) {
    void* p = ws + o;
    o = (o + bytes + 255) & ~(size_t)255;
    return p;
  };
  // region 0: A+BT live only until gemm_qkv; Hb (written by attn, later) aliases them.
  char* region0 = (char*)alloc((size_t)N_PTS * 1280 * 2);  // 20.97 MB
  __bf16* A = (__bf16*)region0;                      // 8 MB
  __bf16* BT = (__bf16*)(region0 + (size_t)N_PTS * CIN * 2);  // 1.5 MB
  __bf16* Hb = (__bf16*)region0;                     // aliases A/BT after gemm
  __bf16* qb = (__bf16*)alloc((size_t)N_PTS * 512 * 2);
  __bf16* kb = (__bf16*)alloc((size_t)N_PTS * 512 * 2);
  __bf16* vb = (__bf16*)alloc((size_t)N_PTS * 512 * 2);
  __bf16* qtb = (__bf16*)alloc((size_t)8 * 144 * 64 * 2);
  __bf16* ktb = (__bf16*)alloc((size_t)8 * 144 * 64 * 2);
  __bf16* vtT = (__bf16*)alloc((size_t)8 * 64 * 160 * 2);
  __bf16* qdot = (__bf16*)alloc((size_t)N_PTS * 1152 * 2);
  __bf16* kdot = (__bf16*)alloc((size_t)N_PTS * 1152 * 2);
  float* den = (float*)alloc((size_t)N_PTS * 8 * 4);
  int* qi_a = (int*)alloc(M_EDGES * 4);
  unsigned* pack0 = (unsigned*)alloc(M_EDGES * 4);
  unsigned* epack = (unsigned*)alloc(M_EDGES * 4);
  int* cnt = (int*)alloc(N_PTS * 4);
  int* off = (int*)alloc((N_PTS + 1) * 4);
  int* cursor = (int*)alloc(N_PTS * 4);

  hipMemsetAsync(cnt, 0, N_PTS * 4, stream);

  prep_kernel<<<5984, 256, 0, stream>>>(xF, W, qt, kt, vt, pairs, xC,
                                        A, BT, qtb, ktb, vtT, qi_a, pack0, cnt);
  scan_kernel<<<1, 256, 0, stream>>>(cnt, off, cursor);
  scatter_k<<<M_EDGES / 256, 256, 0, stream>>>(qi_a, pack0, cursor, epack);
  gemm_qkv<<<dim3(QKV_COLS / 128, N_PTS / 64), 256, 0, stream>>>(A, BT, bias, qb, kb, vb);
  table_dot<<<dim3(N_PTS / 128, 8, 2), 256, 0, stream>>>(qb, kb, qtb, ktb, qdot, kdot);
  attn_kernel<<<N_PTS, 512, 0, stream>>>(qb, kb, vb, qdot, kdot, off, epack, out, den, Hb);
  finish_kernel<<<dim3(N_PTS / 128, 8), 256, 0, stream>>>(Hb, vtT, den, out);
}